// Round 12
// baseline (294.936 us; speedup 1.0000x reference)
//
#include <hip/hip_runtime.h>

using u16 = unsigned short;
using u32 = unsigned int;
using u8 = unsigned char;
typedef __attribute__((ext_vector_type(8))) short short8;   // 8 bf16 (4 VGPRs)
typedef __attribute__((ext_vector_type(4))) float f32x4;    // MFMA acc

static inline int idiv_up(long a, long b) { return (int)((a + b - 1) / b); }

#define NBUCK 256        // dst-range buckets (rangeSize = ceil(N/256) <= 512)
#define ECHUNK 8192      // edges per bucketing block (64KB LDS stash)
#define CAPE 9216        // stage/LDS capacity per bucket (exp 6256, sigma 79 -> +37s)

// ---------- bf16 helpers (packed pairs in u32, elem0 = low half) ----------
__device__ __forceinline__ float bflo(u32 p) { return __uint_as_float(p << 16); }
__device__ __forceinline__ float bfhi(u32 p) { return __uint_as_float(p & 0xffff0000u); }
__device__ __forceinline__ u32 f2bf1(float f) {
    u32 x = __float_as_uint(f);
    return (x + 0x7fffu + ((x >> 16) & 1u)) >> 16;   // RNE
}
__device__ __forceinline__ u32 pack2(float lo, float hi) {
    return f2bf1(lo) | (f2bf1(hi) << 16);
}

// ================= cast x (fp32) -> xb (bf16) =================
__global__ __launch_bounds__(256) void k_cast(const float* __restrict__ x,
                                              u32* __restrict__ xb, long nelem) {
    long i = ((long)blockIdx.x * 256 + threadIdx.x) * 8;
    if (i >= nelem) return;
    float4 v0 = *(const float4*)(x + i);
    float4 v1 = *(const float4*)(x + i + 4);
    uint4 o;
    o.x = pack2(v0.x, v0.y);
    o.y = pack2(v0.z, v0.w);
    o.z = pack2(v1.x, v1.y);
    o.w = pack2(v1.z, v1.w);
    *(uint4*)(xb + (i >> 1)) = o;
}

// ====== W prep: [Wl;Wr] (256x128 fp32) -> MFMA B-fragment-native bf16 ======
__global__ __launch_bounds__(256) void k_wprep(const float* __restrict__ Wl,
                                               const float* __restrict__ Wr,
                                               u16* __restrict__ wp) {
    const int gid = blockIdx.x * 256 + threadIdx.x;
    if (gid >= 64 * 64) return;
    const int tile = gid >> 6, l = gid & 63;
    const int t = tile >> 3, s = tile & 7;
    const int n = t * 16 + (l & 15);
    const int k0 = s * 32 + (l >> 4) * 8;
    u32 w[4];
#pragma unroll
    for (int p = 0; p < 4; ++p) {
        const int ka = k0 + 2 * p, kb = ka + 1;
        const float va = (ka < 128) ? Wl[ka * 128 + n] : Wr[(ka - 128) * 128 + n];
        const float vb = (kb < 128) ? Wl[kb * 128 + n] : Wr[(kb - 128) * 128 + n];
        w[p] = pack2(va, vb);
    }
    uint4 o = {w[0], w[1], w[2], w[3]};
    *(uint4*)(wp + (size_t)gid * 8) = o;
}

// ====== W prep for layer 3: [Wl3 | Wr3] (128x80) -> 20 B-frag tiles =========
__global__ __launch_bounds__(256) void k_wprep3(const float* __restrict__ Wl,
                                                const float* __restrict__ Wr,
                                                u16* __restrict__ wp) {
    const int gid = blockIdx.x * 256 + threadIdx.x;
    if (gid >= 20 * 64) return;
    const int tile = gid >> 6, l = gid & 63;
    const int t = tile >> 2, s = tile & 3;
    const int c = t * 16 + (l & 15);
    const int k0 = s * 32 + (l >> 4) * 8;
    u32 w[4];
#pragma unroll
    for (int p = 0; p < 4; ++p) {
        const int ka = k0 + 2 * p, kb = ka + 1;
        const float va = (c < 40) ? Wl[ka * 40 + c] : Wr[ka * 40 + (c - 40)];
        const float vb = (c < 40) ? Wl[kb * 40 + c] : Wr[kb * 40 + (c - 40)];
        w[p] = pack2(va, vb);
    }
    uint4 o = {w[0], w[1], w[2], w[3]};
    *(uint4*)(wp + (size_t)gid * 8) = o;
}

// ============== CSR build: single-pass LDS bucketing ==============
__global__ __launch_bounds__(256) void k_bucket(const int* __restrict__ src,
                                                const int* __restrict__ dst,
                                                int* __restrict__ cursor,
                                                u32* __restrict__ stage,
                                                int E, int rangeSize) {
    __shared__ u32 s_pay[ECHUNK];
    __shared__ u8 s_bk[ECHUNK];
    __shared__ int s_cnt[NBUCK];
    __shared__ int s_base[NBUCK];
    __shared__ int s_off[NBUCK];
    s_cnt[threadIdx.x] = 0;
    __syncthreads();
    const long e0 = (long)blockIdx.x * ECHUNK;
    const int cnt = (int)(((long)E - e0 < ECHUNK) ? (long)E - e0 : ECHUNK);
    for (int j = threadIdx.x; j < cnt; j += 256) {
        const int d = __builtin_nontemporal_load(&dst[e0 + j]);
        const int s = __builtin_nontemporal_load(&src[e0 + j]);
        const int b = d / rangeSize;
        s_pay[j] = (u32)s | ((u32)(d - b * rangeSize) << 17);
        s_bk[j] = (u8)b;
        atomicAdd(&s_cnt[b], 1);
    }
    __syncthreads();
    {
        const int c = s_cnt[threadIdx.x];
        s_base[threadIdx.x] = c ? atomicAdd(&cursor[threadIdx.x], c) : 0;
        s_off[threadIdx.x] = 0;
    }
    __syncthreads();
    for (int j = threadIdx.x; j < cnt; j += 256) {
        const int b = s_bk[j];
        const int p = atomicAdd(&s_off[b], 1);
        stage[(size_t)b * CAPE + s_base[b] + p] = s_pay[j];
    }
}

// exclusive scan of the 256 bucket counts -> global CSR bucket offsets
__global__ __launch_bounds__(256) void k_bscan(const int* __restrict__ cursor,
                                               int* __restrict__ bbase, int E) {
    __shared__ int wt[4];
    const int t = threadIdx.x;
    const int v = cursor[t];
    const int lane = t & 63, wid = t >> 6;
    int incl = v;
    for (int off = 1; off < 64; off <<= 1) {
        int u = __shfl_up(incl, off, 64);
        if (lane >= off) incl += u;
    }
    if (lane == 63) wt[wid] = incl;
    __syncthreads();
    int woff = 0;
    for (int w = 0; w < wid; ++w) woff += wt[w];
    bbase[t] = woff + incl - v;
    if (t == 255) bbase[256] = woff + incl;   // == E
}

// fused CSR: one block per bucket; count/scan/scatter in LDS, coalesced writeout.
__global__ __launch_bounds__(256) void k_csrlds(const u32* __restrict__ stage,
                                                const int* __restrict__ bcnt,
                                                const int* __restrict__ bbase,
                                                int* __restrict__ rowptr,
                                                float* __restrict__ invd,
                                                int* __restrict__ col,
                                                int rangeSize, int n) {
    __shared__ int s_cnt[512];
    __shared__ int s_cur[512];
    __shared__ int s_col[CAPE];
    __shared__ int wt[4];
    const int b = blockIdx.x;
    const int t = threadIdx.x;
    const int g0 = b * rangeSize;
    const size_t rd = (size_t)b * CAPE;
    const int cntb = bcnt[b];
    const int gbase = bbase[b];

    for (int i = t; i < rangeSize; i += 256) s_cnt[i] = 0;
    __syncthreads();

    for (int i = t; i < cntb; i += 256)
        atomicAdd(&s_cnt[stage[rd + i] >> 17], 1);
    __syncthreads();

    const int i0 = 2 * t, i1 = 2 * t + 1;
    const int c0 = (i0 < rangeSize) ? s_cnt[i0] : 0;
    const int c1 = (i1 < rangeSize) ? s_cnt[i1] : 0;
    const int sum = c0 + c1;
    const int lane = t & 63, wid = t >> 6;
    int incl = sum;
    for (int off = 1; off < 64; off <<= 1) {
        int u = __shfl_up(incl, off, 64);
        if (lane >= off) incl += u;
    }
    if (lane == 63) wt[wid] = incl;
    __syncthreads();
    int woff = 0;
    for (int w = 0; w < wid; ++w) woff += wt[w];
    const int excl = woff + incl - sum;
    if (i0 < rangeSize) {
        s_cur[i0] = excl;
        const int g = g0 + i0;
        if (g <= n) rowptr[g] = gbase + excl;
        if (g < n) invd[g] = 1.0f / fmaxf((float)c0, 1.0f);
    }
    if (i1 < rangeSize) {
        s_cur[i1] = excl + c0;
        const int g = g0 + i1;
        if (g <= n) rowptr[g] = gbase + excl + c0;
        if (g < n) invd[g] = 1.0f / fmaxf((float)c1, 1.0f);
    }
    __syncthreads();

    for (int i = t; i < cntb; i += 256) {
        const u32 v = stage[rd + i];
        const int p = atomicAdd(&s_cur[v >> 17], 1);
        s_col[p] = (int)(v & 0x1FFFFu);
    }
    __syncthreads();

    for (int i = t; i < cntb; i += 256) col[gbase + i] = s_col[i];
}

// ====== FUSED: mean-aggregate (gather) + MFMA SAGE linear ======
// Block = 64 nodes, 17.4 KB LDS (agg tile only -> 8 blocks/CU, 32 waves/CU).
// Phase 1: 16 lanes/node gather -> mean -> LDS cols 0..127 (bf16).
// Phase 2: MFMA [agg|x] @ [Wl;Wr]; agg A-frags from LDS, x A-frags loaded
// DIRECTLY from global (row-local, L2-hot). Rows >= n: A row r only feeds
// D row r, which is never stored; loads clamped to row n-1.
#define ACC8(A, B, V)                                                          \
    A.x += bflo(V.x); A.y += bfhi(V.x); A.z += bflo(V.y); A.w += bfhi(V.y);    \
    B.x += bflo(V.z); B.y += bfhi(V.z); B.z += bflo(V.w); B.w += bfhi(V.w);

__global__ __launch_bounds__(256, 8) void k_aggmm(const u16* __restrict__ xb,
                                                  const int* __restrict__ rowptr,
                                                  const int* __restrict__ col,
                                                  const float* __restrict__ invd,
                                                  const u16* __restrict__ wp,
                                                  const float* __restrict__ bl,
                                                  u16* __restrict__ outb, int n) {
    __shared__ __align__(16) u16 s_a[64][136];
    const int row0 = blockIdx.x * 64;
    const int tid = threadIdx.x;
    const int l = tid & 15;

    // ---- phase 1: aggregate 64 nodes (4 passes of 16 nodes, 16 lanes each) ----
#pragma unroll
    for (int it = 0; it < 4; ++it) {
        const int r = it * 16 + (tid >> 4);
        const int node = row0 + r;
        float4 eA0 = {0.f, 0.f, 0.f, 0.f}, eA1 = {0.f, 0.f, 0.f, 0.f};
        float4 eB0 = {0.f, 0.f, 0.f, 0.f}, eB1 = {0.f, 0.f, 0.f, 0.f};
        float inv = 0.f;
        if (node < n) {
            inv = invd[node];
            const int s0 = rowptr[node], s1 = rowptr[node + 1];
            for (int cb = s0; cb < s1; cb += 16) {
                const int cnt = min(16, s1 - cb);
                const int cc = (cb + l < s1) ? col[cb + l] : 0;
                int j = 0;
                for (; j + 4 <= cnt; j += 4) {
                    const int n0 = __shfl(cc, j, 16);
                    const int n1 = __shfl(cc, j + 1, 16);
                    const int n2 = __shfl(cc, j + 2, 16);
                    const int n3 = __shfl(cc, j + 3, 16);
                    const uint4 v0 = *(const uint4*)(xb + (size_t)n0 * 128 + 8 * l);
                    const uint4 v1 = *(const uint4*)(xb + (size_t)n1 * 128 + 8 * l);
                    const uint4 v2 = *(const uint4*)(xb + (size_t)n2 * 128 + 8 * l);
                    const uint4 v3 = *(const uint4*)(xb + (size_t)n3 * 128 + 8 * l);
                    ACC8(eA0, eA1, v0); ACC8(eB0, eB1, v1);
                    ACC8(eA0, eA1, v2); ACC8(eB0, eB1, v3);
                }
                for (; j < cnt; ++j) {
                    const int nn = __shfl(cc, j, 16);
                    const uint4 v = *(const uint4*)(xb + (size_t)nn * 128 + 8 * l);
                    ACC8(eA0, eA1, v);
                }
            }
        }
        uint4 o;
        o.x = pack2((eA0.x + eB0.x) * inv, (eA0.y + eB0.y) * inv);
        o.y = pack2((eA0.z + eB0.z) * inv, (eA0.w + eB0.w) * inv);
        o.z = pack2((eA1.x + eB1.x) * inv, (eA1.y + eB1.y) * inv);
        o.w = pack2((eA1.z + eB1.z) * inv, (eA1.w + eB1.w) * inv);
        *(uint4*)(&s_a[r][8 * l]) = o;
    }
    __syncthreads();

    // ---- phase 2: MFMA [agg|x] @ [Wl;Wr], s-outer to keep VGPRs <= 64 ----
    const int l64 = tid & 63;
    const int w = tid >> 6;
    const int rloc = w * 16 + (l64 & 15);
    const int q = l64 >> 4;
    const int rowc = min(row0 + rloc, n - 1);   // clamp for x-frag loads

    f32x4 acc[8];
#pragma unroll
    for (int t = 0; t < 8; ++t) acc[t] = (f32x4){0.f, 0.f, 0.f, 0.f};

#pragma unroll
    for (int s = 0; s < 8; ++s) {
        const short8 a = (s < 4)
            ? *(const short8*)(&s_a[rloc][s * 32 + q * 8])
            : *(const short8*)(xb + (size_t)rowc * 128 + (s - 4) * 32 + q * 8);
#pragma unroll
        for (int t = 0; t < 8; ++t) {
            const short8 b = *(const short8*)(wp + ((size_t)(t * 8 + s) * 64 + l64) * 8);
            acc[t] = __builtin_amdgcn_mfma_f32_16x16x32_bf16(a, b, acc[t], 0, 0, 0);
        }
    }

    const int rowb = row0 + w * 16 + q * 4;
#pragma unroll
    for (int t = 0; t < 8; ++t) {
        const float bias = bl[t * 16 + (l64 & 15)];
#pragma unroll
        for (int r = 0; r < 4; ++r) {
            const int row = rowb + r;
            if (row < n) {
                const float o = fmaxf(acc[t][r] + bias, 0.f);
                outb[(size_t)row * 128 + t * 16 + (l64 & 15)] = (u16)f2bf1(o);
            }
        }
    }
}

// ====== layer 3 transform via MFMA: [t40 | r40] = h2 @ [Wl3 | Wr3] ==========
__global__ __launch_bounds__(256, 4) void k_mm40f(const u16* __restrict__ hb,
                                                  const u16* __restrict__ wp,
                                                  const float* __restrict__ bl,
                                                  u16* __restrict__ t40b,
                                                  float* __restrict__ r40, int n) {
    __shared__ __align__(16) u16 s_a[64][136];
    const int row0 = blockIdx.x * 64;
    const int tid = threadIdx.x;

#pragma unroll
    for (int it = 0; it < 4; ++it) {
        const int idx = tid + it * 256;
        const int r = idx >> 4, c8 = idx & 15;
        const int row = row0 + r;
        uint4 v = {0u, 0u, 0u, 0u};
        if (row < n) v = *(const uint4*)(hb + (size_t)row * 128 + c8 * 8);
        *(uint4*)(&s_a[r][c8 * 8]) = v;
    }
    __syncthreads();

    const int l = tid & 63;
    const int w = tid >> 6;
    const int rloc = w * 16 + (l & 15);
    const int q = l >> 4;

    short8 afr[4];
#pragma unroll
    for (int s = 0; s < 4; ++s)
        afr[s] = *(const short8*)(&s_a[rloc][s * 32 + q * 8]);

    f32x4 acc[5];
#pragma unroll
    for (int t = 0; t < 5; ++t) acc[t] = (f32x4){0.f, 0.f, 0.f, 0.f};

#pragma unroll
    for (int t = 0; t < 5; ++t) {
#pragma unroll
        for (int s = 0; s < 4; ++s) {
            const short8 b = *(const short8*)(wp + ((size_t)(t * 4 + s) * 64 + l) * 8);
            acc[t] = __builtin_amdgcn_mfma_f32_16x16x32_bf16(afr[s], b, acc[t], 0, 0, 0);
        }
    }

    const int rowb = row0 + w * 16 + q * 4;
#pragma unroll
    for (int t = 0; t < 5; ++t) {
        const int c = t * 16 + (l & 15);
        const float bias = (c >= 40) ? bl[c - 40] : 0.f;
#pragma unroll
        for (int r = 0; r < 4; ++r) {
            const int row = rowb + r;
            if (row < n) {
                if (c < 40)
                    t40b[(size_t)row * 40 + c] = (u16)f2bf1(acc[t][r]);
                else
                    r40[(size_t)row * 40 + (c - 40)] = acc[t][r] + bias;
            }
        }
    }
}

// ================= layer 3 aggregation (d=40): out = invd*sum(t[nbr]) + r ====
#define ACC4(A, V)                                                     \
    A.x += bflo(V.x); A.y += bfhi(V.x); A.z += bflo(V.y); A.w += bfhi(V.y);

__global__ __launch_bounds__(256) void k_agg40(const u16* __restrict__ t40b,
                                               const float* __restrict__ r40,
                                               const int* __restrict__ rowptr,
                                               const int* __restrict__ col,
                                               const float* __restrict__ invd,
                                               float* __restrict__ out, int n) {
    const int tt = blockIdx.x * 256 + threadIdx.x;
    const int node = tt >> 4;
    if (node >= n) return;
    const int l = tt & 15;
    const bool act = l < 10;
    const int s0 = rowptr[node], s1 = rowptr[node + 1];
    float4 a0 = {0.f, 0.f, 0.f, 0.f};
    float4 a1 = {0.f, 0.f, 0.f, 0.f};
    for (int cb = s0; cb < s1; cb += 16) {
        const int cnt = min(16, s1 - cb);
        const int cc = (cb + l < s1) ? col[cb + l] : 0;
        int j = 0;
        for (; j + 4 <= cnt; j += 4) {
            const int n0 = __shfl(cc, j, 16);
            const int n1 = __shfl(cc, j + 1, 16);
            const int n2 = __shfl(cc, j + 2, 16);
            const int n3 = __shfl(cc, j + 3, 16);
            if (act) {
                const uint2 v0 = *(const uint2*)(t40b + (size_t)n0 * 40 + 4 * l);
                const uint2 v1 = *(const uint2*)(t40b + (size_t)n1 * 40 + 4 * l);
                const uint2 v2 = *(const uint2*)(t40b + (size_t)n2 * 40 + 4 * l);
                const uint2 v3 = *(const uint2*)(t40b + (size_t)n3 * 40 + 4 * l);
                ACC4(a0, v0); ACC4(a1, v1); ACC4(a0, v2); ACC4(a1, v3);
            }
        }
        for (; j < cnt; ++j) {
            const int nn = __shfl(cc, j, 16);
            if (act) {
                const uint2 v = *(const uint2*)(t40b + (size_t)nn * 40 + 4 * l);
                ACC4(a0, v);
            }
        }
    }
    if (act) {
        const float inv = invd[node];
        const float4 rv = *(const float4*)(r40 + (size_t)node * 40 + 4 * l);
        float4 o;
        o.x = fmaf(a0.x + a1.x, inv, rv.x);
        o.y = fmaf(a0.y + a1.y, inv, rv.y);
        o.z = fmaf(a0.z + a1.z, inv, rv.z);
        o.w = fmaf(a0.w + a1.w, inv, rv.w);
        *(float4*)(out + (size_t)node * 40 + 4 * l) = o;
    }
}

extern "C" void kernel_launch(void* const* d_in, const int* in_sizes, int n_in,
                              void* d_out, int out_size, void* d_ws, size_t ws_size,
                              hipStream_t stream) {
    const float* x   = (const float*)d_in[0];
    const int*   ei  = (const int*)d_in[1];
    const float* Wl1 = (const float*)d_in[2];
    const float* bl1 = (const float*)d_in[3];
    const float* Wr1 = (const float*)d_in[4];
    const float* Wl2 = (const float*)d_in[5];
    const float* bl2 = (const float*)d_in[6];
    const float* Wr2 = (const float*)d_in[7];
    const float* Wl3 = (const float*)d_in[8];
    const float* bl3 = (const float*)d_in[9];
    const float* Wr3 = (const float*)d_in[10];
    float* out = (float*)d_out;

    const int N = in_sizes[0] / 128;
    const int E = in_sizes[1] / 2;
    const int* src = ei;
    const int* dst = ei + E;

    auto align1k = [](size_t v) { return (v + 1023) & ~(size_t)1023; };
    const size_t NB16 = (size_t)N * 128 * sizeof(u16);   // 25.6 MB

    char* ws = (char*)d_ws;
    size_t off = 0;
    float* invd     = (float*)(ws + off); off += align1k((size_t)N * 4);
    int*   rowptr   = (int*)(ws + off);   off += align1k((size_t)(N + 1) * 4);
    int*   cursor   = (int*)(ws + off);   off += align1k(NBUCK * 4);
    int*   bbase    = (int*)(ws + off);   off += align1k((NBUCK + 1) * 4);
    u16*   wp1      = (u16*)(ws + off);   off += align1k(64 * 1024);
    u16*   wp2      = (u16*)(ws + off);   off += align1k(64 * 1024);
    u16*   wp3      = (u16*)(ws + off);   off += align1k(20 * 1024);
    int*   col      = (int*)(ws + off);   off += align1k((size_t)E * 4);
    u32*   stage    = (u32*)(ws + off);   off += align1k((size_t)NBUCK * CAPE * 4);
    u16*   xb       = (u16*)(ws + off);   off += align1k(NB16);   // later: h2b
    char*  regionY  = (ws + off);         off += align1k(NB16);   // h1b, later t40b+r40
    u16*   h1b  = (u16*)regionY;
    u16*   h2b  = xb;
    u16*   t40b = (u16*)regionY;
    float* r40  = (float*)(regionY + align1k((size_t)N * 40 * sizeof(u16)));

    const int nPB        = idiv_up(E, ECHUNK);
    const int castBlocks = idiv_up((long)N * 128, 2048);
    const int agg40Blk   = idiv_up((long)N * 16, 256);
    const int mmBlocks   = idiv_up(N, 64);
    const int rangeSize  = idiv_up(N, NBUCK);   // 391

    // ---- cast x -> bf16 ; W preps ----
    k_cast<<<castBlocks, 256, 0, stream>>>(x, (u32*)xb, (long)N * 128);
    k_wprep<<<16, 256, 0, stream>>>(Wl1, Wr1, wp1);
    k_wprep<<<16, 256, 0, stream>>>(Wl2, Wr2, wp2);
    k_wprep3<<<5, 256, 0, stream>>>(Wl3, Wr3, wp3);

    // ---- CSR build: single-pass LDS bucketing + LDS CSR ----
    hipMemsetAsync(cursor, 0, NBUCK * sizeof(int), stream);
    k_bucket<<<nPB, 256, 0, stream>>>(src, dst, cursor, stage, E, rangeSize);
    k_bscan<<<1, 256, 0, stream>>>(cursor, bbase, E);
    k_csrlds<<<NBUCK, 256, 0, stream>>>(stage, cursor, bbase, rowptr, invd, col,
                                        rangeSize, N);

    // ---- layer 1 (fused gather + MFMA) ----
    k_aggmm<<<mmBlocks, 256, 0, stream>>>(xb, rowptr, col, invd, wp1, bl1, h1b, N);

    // ---- layer 2 (fused) ----
    k_aggmm<<<mmBlocks, 256, 0, stream>>>(h1b, rowptr, col, invd, wp2, bl2, h2b, N);

    // ---- layer 3: transform-then-aggregate over d=40 (MFMA transform) ----
    k_mm40f<<<mmBlocks, 256, 0, stream>>>(h2b, wp3, bl3, t40b, r40, N);
    k_agg40<<<agg40Blk, 256, 0, stream>>>(t40b, r40, rowptr, col, invd, out, N);
}

// Round 13
// 287.736 us; speedup vs baseline: 1.0250x; 1.0250x over previous
//
#include <hip/hip_runtime.h>

using u16 = unsigned short;
using u32 = unsigned int;
using u8 = unsigned char;
typedef __attribute__((ext_vector_type(8))) short short8;   // 8 bf16 (4 VGPRs)
typedef __attribute__((ext_vector_type(4))) float f32x4;    // MFMA acc

static inline int idiv_up(long a, long b) { return (int)((a + b - 1) / b); }

#define NBUCK 256        // dst-range buckets (rangeSize = ceil(N/256) <= 512)
#define ECHUNK 8192      // edges per bucketing block (64KB LDS stash)
#define CAPE 9216        // stage/LDS capacity per bucket (exp 6256, sigma 79 -> +37s)

// ---------- bf16 helpers (packed pairs in u32, elem0 = low half) ----------
__device__ __forceinline__ float bflo(u32 p) { return __uint_as_float(p << 16); }
__device__ __forceinline__ float bfhi(u32 p) { return __uint_as_float(p & 0xffff0000u); }
__device__ __forceinline__ u32 f2bf1(float f) {
    u32 x = __float_as_uint(f);
    return (x + 0x7fffu + ((x >> 16) & 1u)) >> 16;   // RNE
}
__device__ __forceinline__ u32 pack2(float lo, float hi) {
    return f2bf1(lo) | (f2bf1(hi) << 16);
}

// ================= cast x (fp32) -> xb (bf16) =================
__global__ __launch_bounds__(256) void k_cast(const float* __restrict__ x,
                                              u32* __restrict__ xb, long nelem) {
    long i = ((long)blockIdx.x * 256 + threadIdx.x) * 8;
    if (i >= nelem) return;
    float4 v0 = *(const float4*)(x + i);
    float4 v1 = *(const float4*)(x + i + 4);
    uint4 o;
    o.x = pack2(v0.x, v0.y);
    o.y = pack2(v0.z, v0.w);
    o.z = pack2(v1.x, v1.y);
    o.w = pack2(v1.z, v1.w);
    *(uint4*)(xb + (i >> 1)) = o;
}

// ====== combined W prep (one launch): blocks 0-15 -> wp1, 16-31 -> wp2,
// 32-36 -> wp3. 128x128-pair preps use tile/t/s layout of k_wprep; layer-3
// uses 20-tile layout. All fragment-native bf16, one uint4 per (tile,lane).
__global__ __launch_bounds__(256) void k_wprepall(const float* __restrict__ Wl1,
                                                  const float* __restrict__ Wr1,
                                                  const float* __restrict__ Wl2,
                                                  const float* __restrict__ Wr2,
                                                  const float* __restrict__ Wl3,
                                                  const float* __restrict__ Wr3,
                                                  u16* __restrict__ wp1,
                                                  u16* __restrict__ wp2,
                                                  u16* __restrict__ wp3) {
    const int b = blockIdx.x;
    if (b < 32) {
        const float* Wl = (b < 16) ? Wl1 : Wl2;
        const float* Wr = (b < 16) ? Wr1 : Wr2;
        u16* wp = (b < 16) ? wp1 : wp2;
        const int gid = (b & 15) * 256 + threadIdx.x;
        const int tile = gid >> 6, l = gid & 63;
        const int t = tile >> 3, s = tile & 7;
        const int n = t * 16 + (l & 15);
        const int k0 = s * 32 + (l >> 4) * 8;
        u32 w[4];
#pragma unroll
        for (int p = 0; p < 4; ++p) {
            const int ka = k0 + 2 * p, kb = ka + 1;
            const float va = (ka < 128) ? Wl[ka * 128 + n] : Wr[(ka - 128) * 128 + n];
            const float vb = (kb < 128) ? Wl[kb * 128 + n] : Wr[(kb - 128) * 128 + n];
            w[p] = pack2(va, vb);
        }
        uint4 o = {w[0], w[1], w[2], w[3]};
        *(uint4*)(wp + (size_t)gid * 8) = o;
    } else {
        const int gid = (b - 32) * 256 + threadIdx.x;
        if (gid >= 20 * 64) return;
        const int tile = gid >> 6, l = gid & 63;
        const int t = tile >> 2, s = tile & 3;
        const int c = t * 16 + (l & 15);
        const int k0 = s * 32 + (l >> 4) * 8;
        u32 w[4];
#pragma unroll
        for (int p = 0; p < 4; ++p) {
            const int ka = k0 + 2 * p, kb = ka + 1;
            const float va = (c < 40) ? Wl3[ka * 40 + c] : Wr3[ka * 40 + (c - 40)];
            const float vb = (c < 40) ? Wl3[kb * 40 + c] : Wr3[kb * 40 + (c - 40)];
            w[p] = pack2(va, vb);
        }
        uint4 o = {w[0], w[1], w[2], w[3]};
        *(uint4*)(wp3 + (size_t)gid * 8) = o;
    }
}

// ============== CSR build: single-pass LDS bucketing ==============
__global__ __launch_bounds__(256) void k_bucket(const int* __restrict__ src,
                                                const int* __restrict__ dst,
                                                int* __restrict__ cursor,
                                                u32* __restrict__ stage,
                                                int E, int rangeSize) {
    __shared__ u32 s_pay[ECHUNK];
    __shared__ u8 s_bk[ECHUNK];
    __shared__ int s_cnt[NBUCK];
    __shared__ int s_base[NBUCK];
    __shared__ int s_off[NBUCK];
    s_cnt[threadIdx.x] = 0;
    __syncthreads();
    const long e0 = (long)blockIdx.x * ECHUNK;
    const int cnt = (int)(((long)E - e0 < ECHUNK) ? (long)E - e0 : ECHUNK);
    for (int j = threadIdx.x; j < cnt; j += 256) {
        const int d = __builtin_nontemporal_load(&dst[e0 + j]);
        const int s = __builtin_nontemporal_load(&src[e0 + j]);
        const int b = d / rangeSize;
        s_pay[j] = (u32)s | ((u32)(d - b * rangeSize) << 17);
        s_bk[j] = (u8)b;
        atomicAdd(&s_cnt[b], 1);
    }
    __syncthreads();
    {
        const int c = s_cnt[threadIdx.x];
        s_base[threadIdx.x] = c ? atomicAdd(&cursor[threadIdx.x], c) : 0;
        s_off[threadIdx.x] = 0;
    }
    __syncthreads();
    for (int j = threadIdx.x; j < cnt; j += 256) {
        const int b = s_bk[j];
        const int p = atomicAdd(&s_off[b], 1);
        stage[(size_t)b * CAPE + s_base[b] + p] = s_pay[j];
    }
}

// fused CSR: one block per bucket. Inline 256-wide scan of bucket counts gives
// this bucket's global base; then count/scan/scatter in LDS, coalesced writeout.
__global__ __launch_bounds__(256) void k_csrlds(const u32* __restrict__ stage,
                                                const int* __restrict__ cursor,
                                                int* __restrict__ rowptr,
                                                float* __restrict__ invd,
                                                int* __restrict__ col,
                                                int rangeSize, int n) {
    __shared__ int s_cnt[512];
    __shared__ int s_cur[512];
    __shared__ int s_col[CAPE];
    __shared__ int wt[4];
    __shared__ int sh_gbase;
    const int b = blockIdx.x;
    const int t = threadIdx.x;
    const int g0 = b * rangeSize;
    const size_t rd = (size_t)b * CAPE;

    // inline exclusive scan of cursor[0..255] -> this bucket's global base
    {
        const int v = cursor[t];
        const int lane = t & 63, wid = t >> 6;
        int incl = v;
        for (int off = 1; off < 64; off <<= 1) {
            int u = __shfl_up(incl, off, 64);
            if (lane >= off) incl += u;
        }
        if (lane == 63) wt[wid] = incl;
        __syncthreads();
        int woff = 0;
        for (int w = 0; w < wid; ++w) woff += wt[w];
        if (t == b) sh_gbase = woff + incl - v;
    }
    __syncthreads();
    const int cntb = cursor[b];
    const int gbase = sh_gbase;

    for (int i = t; i < rangeSize; i += 256) s_cnt[i] = 0;
    __syncthreads();

    for (int i = t; i < cntb; i += 256)
        atomicAdd(&s_cnt[stage[rd + i] >> 17], 1);
    __syncthreads();

    const int i0 = 2 * t, i1 = 2 * t + 1;
    const int c0 = (i0 < rangeSize) ? s_cnt[i0] : 0;
    const int c1 = (i1 < rangeSize) ? s_cnt[i1] : 0;
    const int sum = c0 + c1;
    const int lane = t & 63, wid = t >> 6;
    int incl = sum;
    for (int off = 1; off < 64; off <<= 1) {
        int u = __shfl_up(incl, off, 64);
        if (lane >= off) incl += u;
    }
    __syncthreads();   // wt reuse
    if (lane == 63) wt[wid] = incl;
    __syncthreads();
    int woff = 0;
    for (int w = 0; w < wid; ++w) woff += wt[w];
    const int excl = woff + incl - sum;
    if (i0 < rangeSize) {
        s_cur[i0] = excl;
        const int g = g0 + i0;
        if (g <= n) rowptr[g] = gbase + excl;
        if (g < n) invd[g] = 1.0f / fmaxf((float)c0, 1.0f);
    }
    if (i1 < rangeSize) {
        s_cur[i1] = excl + c0;
        const int g = g0 + i1;
        if (g <= n) rowptr[g] = gbase + excl + c0;
        if (g < n) invd[g] = 1.0f / fmaxf((float)c1, 1.0f);
    }
    __syncthreads();

    for (int i = t; i < cntb; i += 256) {
        const u32 v = stage[rd + i];
        const int p = atomicAdd(&s_cur[v >> 17], 1);
        s_col[p] = (int)(v & 0x1FFFFu);
    }
    __syncthreads();

    for (int i = t; i < cntb; i += 256) col[gbase + i] = s_col[i];
}

// ====== FUSED: mean-aggregate (gather) + MFMA SAGE linear ======
// Block = 64 nodes, 17.4 KB LDS -> 8 blocks/CU. Phase 1: 32 lanes/node,
// uint2 loads, 8-deep batch (round-9 proven gather shape) -> mean bf16 into
// LDS cols 0..127. Phase 2: MFMA [agg|x]@[Wl;Wr]; agg frags from LDS, x
// frags direct from global (wave-line-coherent). Phase 3: results bounce
// through LDS (wave-disjoint row slices) -> coalesced uint4 stores.
#define ACC4(A, V)                                                     \
    A.x += bflo(V.x); A.y += bfhi(V.x); A.z += bflo(V.y); A.w += bfhi(V.y);

__global__ __launch_bounds__(256, 8) void k_aggmm(const u16* __restrict__ xb,
                                                  const int* __restrict__ rowptr,
                                                  const int* __restrict__ col,
                                                  const float* __restrict__ invd,
                                                  const u16* __restrict__ wp,
                                                  const float* __restrict__ bl,
                                                  u16* __restrict__ outb, int n) {
    __shared__ __align__(16) u16 s_a[64][136];
    const int row0 = blockIdx.x * 64;
    const int tid = threadIdx.x;

    // ---- phase 1: aggregate 64 nodes (8 passes of 8 nodes, 32 lanes each) ----
    const int l32 = tid & 31;
#pragma unroll
    for (int it = 0; it < 8; ++it) {
        const int r = it * 8 + (tid >> 5);
        const int node = row0 + r;
        float4 a0 = {0.f, 0.f, 0.f, 0.f};
        float4 a1 = {0.f, 0.f, 0.f, 0.f};
        float inv = 0.f;
        if (node < n) {
            inv = invd[node];
            const int s0 = rowptr[node], s1 = rowptr[node + 1];
            for (int cb = s0; cb < s1; cb += 32) {
                const int cnt = min(32, s1 - cb);
                const int cc = (cb + l32 < s1) ? col[cb + l32] : 0;
                int j = 0;
                for (; j + 8 <= cnt; j += 8) {
                    const int n0 = __shfl(cc, j, 32);
                    const int n1 = __shfl(cc, j + 1, 32);
                    const int n2 = __shfl(cc, j + 2, 32);
                    const int n3 = __shfl(cc, j + 3, 32);
                    const int n4 = __shfl(cc, j + 4, 32);
                    const int n5 = __shfl(cc, j + 5, 32);
                    const int n6 = __shfl(cc, j + 6, 32);
                    const int n7 = __shfl(cc, j + 7, 32);
                    const uint2 v0 = *(const uint2*)(xb + (size_t)n0 * 128 + 4 * l32);
                    const uint2 v1 = *(const uint2*)(xb + (size_t)n1 * 128 + 4 * l32);
                    const uint2 v2 = *(const uint2*)(xb + (size_t)n2 * 128 + 4 * l32);
                    const uint2 v3 = *(const uint2*)(xb + (size_t)n3 * 128 + 4 * l32);
                    const uint2 v4 = *(const uint2*)(xb + (size_t)n4 * 128 + 4 * l32);
                    const uint2 v5 = *(const uint2*)(xb + (size_t)n5 * 128 + 4 * l32);
                    const uint2 v6 = *(const uint2*)(xb + (size_t)n6 * 128 + 4 * l32);
                    const uint2 v7 = *(const uint2*)(xb + (size_t)n7 * 128 + 4 * l32);
                    ACC4(a0, v0); ACC4(a1, v1); ACC4(a0, v2); ACC4(a1, v3);
                    ACC4(a0, v4); ACC4(a1, v5); ACC4(a0, v6); ACC4(a1, v7);
                }
                for (; j + 4 <= cnt; j += 4) {
                    const int n0 = __shfl(cc, j, 32);
                    const int n1 = __shfl(cc, j + 1, 32);
                    const int n2 = __shfl(cc, j + 2, 32);
                    const int n3 = __shfl(cc, j + 3, 32);
                    const uint2 v0 = *(const uint2*)(xb + (size_t)n0 * 128 + 4 * l32);
                    const uint2 v1 = *(const uint2*)(xb + (size_t)n1 * 128 + 4 * l32);
                    const uint2 v2 = *(const uint2*)(xb + (size_t)n2 * 128 + 4 * l32);
                    const uint2 v3 = *(const uint2*)(xb + (size_t)n3 * 128 + 4 * l32);
                    ACC4(a0, v0); ACC4(a1, v1); ACC4(a0, v2); ACC4(a1, v3);
                }
                for (; j < cnt; ++j) {
                    const int nn = __shfl(cc, j, 32);
                    const uint2 v = *(const uint2*)(xb + (size_t)nn * 128 + 4 * l32);
                    ACC4(a0, v);
                }
            }
        }
        uint2 o;
        o.x = pack2((a0.x + a1.x) * inv, (a0.y + a1.y) * inv);
        o.y = pack2((a0.z + a1.z) * inv, (a0.w + a1.w) * inv);
        *(uint2*)(&s_a[r][4 * l32]) = o;
    }
    __syncthreads();

    // ---- phase 2: MFMA [agg|x] @ [Wl;Wr], s-outer ----
    const int l64 = tid & 63;
    const int w = tid >> 6;
    const int rloc = w * 16 + (l64 & 15);
    const int q = l64 >> 4;
    const int rowc = min(row0 + rloc, n - 1);   // clamp for x-frag loads

    f32x4 acc[8];
#pragma unroll
    for (int t = 0; t < 8; ++t) acc[t] = (f32x4){0.f, 0.f, 0.f, 0.f};

#pragma unroll
    for (int s = 0; s < 8; ++s) {
        const short8 a = (s < 4)
            ? *(const short8*)(&s_a[rloc][s * 32 + q * 8])
            : *(const short8*)(xb + (size_t)rowc * 128 + (s - 4) * 32 + q * 8);
#pragma unroll
        for (int t = 0; t < 8; ++t) {
            const short8 b = *(const short8*)(wp + ((size_t)(t * 8 + s) * 64 + l64) * 8);
            acc[t] = __builtin_amdgcn_mfma_f32_16x16x32_bf16(a, b, acc[t], 0, 0, 0);
        }
    }

    // ---- phase 3: bias+relu -> bf16 into LDS (own wave's 16-row slice), then
    // block-wide coalesced uint4 stores.
    const int cb16 = l64 & 15;
    const int rowl = w * 16 + q * 4;
#pragma unroll
    for (int t = 0; t < 8; ++t) {
        const float bias = bl[t * 16 + cb16];
#pragma unroll
        for (int r = 0; r < 4; ++r) {
            const float o = fmaxf(acc[t][r] + bias, 0.f);
            s_a[rowl + r][t * 16 + cb16] = (u16)f2bf1(o);
        }
    }
    __syncthreads();
#pragma unroll
    for (int it = 0; it < 4; ++it) {
        const int idx = tid + it * 256;
        const int r = idx >> 4, c8 = idx & 15;
        const int row = row0 + r;
        if (row < n)
            *(uint4*)(outb + (size_t)row * 128 + c8 * 8) = *(const uint4*)(&s_a[r][c8 * 8]);
    }
}

// ====== layer 3 transform via MFMA: [t40 | r40] = h2 @ [Wl3 | Wr3] ==========
__global__ __launch_bounds__(256, 4) void k_mm40f(const u16* __restrict__ hb,
                                                  const u16* __restrict__ wp,
                                                  const float* __restrict__ bl,
                                                  u16* __restrict__ t40b,
                                                  float* __restrict__ r40, int n) {
    __shared__ __align__(16) u16 s_a[64][136];
    const int row0 = blockIdx.x * 64;
    const int tid = threadIdx.x;

#pragma unroll
    for (int it = 0; it < 4; ++it) {
        const int idx = tid + it * 256;
        const int r = idx >> 4, c8 = idx & 15;
        const int row = row0 + r;
        uint4 v = {0u, 0u, 0u, 0u};
        if (row < n) v = *(const uint4*)(hb + (size_t)row * 128 + c8 * 8);
        *(uint4*)(&s_a[r][c8 * 8]) = v;
    }
    __syncthreads();

    const int l = tid & 63;
    const int w = tid >> 6;
    const int rloc = w * 16 + (l & 15);
    const int q = l >> 4;

    short8 afr[4];
#pragma unroll
    for (int s = 0; s < 4; ++s)
        afr[s] = *(const short8*)(&s_a[rloc][s * 32 + q * 8]);

    f32x4 acc[5];
#pragma unroll
    for (int t = 0; t < 5; ++t) acc[t] = (f32x4){0.f, 0.f, 0.f, 0.f};

#pragma unroll
    for (int t = 0; t < 5; ++t) {
#pragma unroll
        for (int s = 0; s < 4; ++s) {
            const short8 b = *(const short8*)(wp + ((size_t)(t * 4 + s) * 64 + l) * 8);
            acc[t] = __builtin_amdgcn_mfma_f32_16x16x32_bf16(afr[s], b, acc[t], 0, 0, 0);
        }
    }

    const int rowb = row0 + w * 16 + q * 4;
#pragma unroll
    for (int t = 0; t < 5; ++t) {
        const int c = t * 16 + (l & 15);
        const float bias = (c >= 40) ? bl[c - 40] : 0.f;
#pragma unroll
        for (int r = 0; r < 4; ++r) {
            const int row = rowb + r;
            if (row < n) {
                if (c < 40)
                    t40b[(size_t)row * 40 + c] = (u16)f2bf1(acc[t][r]);
                else
                    r40[(size_t)row * 40 + (c - 40)] = acc[t][r] + bias;
            }
        }
    }
}

// ================= layer 3 aggregation (d=40): out = invd*sum(t[nbr]) + r ====
__global__ __launch_bounds__(256) void k_agg40(const u16* __restrict__ t40b,
                                               const float* __restrict__ r40,
                                               const int* __restrict__ rowptr,
                                               const int* __restrict__ col,
                                               const float* __restrict__ invd,
                                               float* __restrict__ out, int n) {
    const int tt = blockIdx.x * 256 + threadIdx.x;
    const int node = tt >> 4;
    if (node >= n) return;
    const int l = tt & 15;
    const bool act = l < 10;
    const int s0 = rowptr[node], s1 = rowptr[node + 1];
    float4 a0 = {0.f, 0.f, 0.f, 0.f};
    float4 a1 = {0.f, 0.f, 0.f, 0.f};
    for (int cb = s0; cb < s1; cb += 16) {
        const int cnt = min(16, s1 - cb);
        const int cc = (cb + l < s1) ? col[cb + l] : 0;
        int j = 0;
        for (; j + 4 <= cnt; j += 4) {
            const int n0 = __shfl(cc, j, 16);
            const int n1 = __shfl(cc, j + 1, 16);
            const int n2 = __shfl(cc, j + 2, 16);
            const int n3 = __shfl(cc, j + 3, 16);
            if (act) {
                const uint2 v0 = *(const uint2*)(t40b + (size_t)n0 * 40 + 4 * l);
                const uint2 v1 = *(const uint2*)(t40b + (size_t)n1 * 40 + 4 * l);
                const uint2 v2 = *(const uint2*)(t40b + (size_t)n2 * 40 + 4 * l);
                const uint2 v3 = *(const uint2*)(t40b + (size_t)n3 * 40 + 4 * l);
                ACC4(a0, v0); ACC4(a1, v1); ACC4(a0, v2); ACC4(a1, v3);
            }
        }
        for (; j < cnt; ++j) {
            const int nn = __shfl(cc, j, 16);
            if (act) {
                const uint2 v = *(const uint2*)(t40b + (size_t)nn * 40 + 4 * l);
                ACC4(a0, v);
            }
        }
    }
    if (act) {
        const float inv = invd[node];
        const float4 rv = *(const float4*)(r40 + (size_t)node * 40 + 4 * l);
        float4 o;
        o.x = fmaf(a0.x + a1.x, inv, rv.x);
        o.y = fmaf(a0.y + a1.y, inv, rv.y);
        o.z = fmaf(a0.z + a1.z, inv, rv.z);
        o.w = fmaf(a0.w + a1.w, inv, rv.w);
        *(float4*)(out + (size_t)node * 40 + 4 * l) = o;
    }
}

extern "C" void kernel_launch(void* const* d_in, const int* in_sizes, int n_in,
                              void* d_out, int out_size, void* d_ws, size_t ws_size,
                              hipStream_t stream) {
    const float* x   = (const float*)d_in[0];
    const int*   ei  = (const int*)d_in[1];
    const float* Wl1 = (const float*)d_in[2];
    const float* bl1 = (const float*)d_in[3];
    const float* Wr1 = (const float*)d_in[4];
    const float* Wl2 = (const float*)d_in[5];
    const float* bl2 = (const float*)d_in[6];
    const float* Wr2 = (const float*)d_in[7];
    const float* Wl3 = (const float*)d_in[8];
    const float* bl3 = (const float*)d_in[9];
    const float* Wr3 = (const float*)d_in[10];
    float* out = (float*)d_out;

    const int N = in_sizes[0] / 128;
    const int E = in_sizes[1] / 2;
    const int* src = ei;
    const int* dst = ei + E;

    auto align1k = [](size_t v) { return (v + 1023) & ~(size_t)1023; };
    const size_t NB16 = (size_t)N * 128 * sizeof(u16);   // 25.6 MB

    char* ws = (char*)d_ws;
    size_t off = 0;
    float* invd     = (float*)(ws + off); off += align1k((size_t)N * 4);
    int*   rowptr   = (int*)(ws + off);   off += align1k((size_t)(N + 1) * 4);
    int*   cursor   = (int*)(ws + off);   off += align1k(NBUCK * 4);
    u16*   wp1      = (u16*)(ws + off);   off += align1k(64 * 1024);
    u16*   wp2      = (u16*)(ws + off);   off += align1k(64 * 1024);
    u16*   wp3      = (u16*)(ws + off);   off += align1k(20 * 1024);
    int*   col      = (int*)(ws + off);   off += align1k((size_t)E * 4);
    u32*   stage    = (u32*)(ws + off);   off += align1k((size_t)NBUCK * CAPE * 4);
    u16*   xb       = (u16*)(ws + off);   off += align1k(NB16);   // later: h2b
    char*  regionY  = (ws + off);         off += align1k(NB16);   // h1b, later t40b+r40
    u16*   h1b  = (u16*)regionY;
    u16*   h2b  = xb;
    u16*   t40b = (u16*)regionY;
    float* r40  = (float*)(regionY + align1k((size_t)N * 40 * sizeof(u16)));

    const int nPB        = idiv_up(E, ECHUNK);
    const int castBlocks = idiv_up((long)N * 128, 2048);
    const int agg40Blk   = idiv_up((long)N * 16, 256);
    const int mmBlocks   = idiv_up(N, 64);
    const int rangeSize  = idiv_up(N, NBUCK);   // 391

    // ---- cast x -> bf16 ; combined W prep ----
    k_cast<<<castBlocks, 256, 0, stream>>>(x, (u32*)xb, (long)N * 128);
    k_wprepall<<<37, 256, 0, stream>>>(Wl1, Wr1, Wl2, Wr2, Wl3, Wr3, wp1, wp2, wp3);

    // ---- CSR build: single-pass LDS bucketing + LDS CSR (scan inlined) ----
    hipMemsetAsync(cursor, 0, NBUCK * sizeof(int), stream);
    k_bucket<<<nPB, 256, 0, stream>>>(src, dst, cursor, stage, E, rangeSize);
    k_csrlds<<<NBUCK, 256, 0, stream>>>(stage, cursor, rowptr, invd, col,
                                        rangeSize, N);

    // ---- layer 1 (fused gather + MFMA) ----
    k_aggmm<<<mmBlocks, 256, 0, stream>>>(xb, rowptr, col, invd, wp1, bl1, h1b, N);

    // ---- layer 2 (fused) ----
    k_aggmm<<<mmBlocks, 256, 0, stream>>>(h1b, rowptr, col, invd, wp2, bl2, h2b, N);

    // ---- layer 3: transform-then-aggregate over d=40 (MFMA transform) ----
    k_mm40f<<<mmBlocks, 256, 0, stream>>>(h2b, wp3, bl3, t40b, r40, N);
    k_agg40<<<agg40Blk, 256, 0, stream>>>(t40b, r40, rowptr, col, invd, out, N);
}